// Round 9
// baseline (215.096 us; speedup 1.0000x reference)
//
#include <hip/hip_runtime.h>
#include <math.h>

#define KK 64
#define DD 256
#define GX 256        // blocks per feature; grid = 512 = 2 blocks/CU
#define CH 16         // rows per MFMA chunk (K of 32x32x16)
#define MAXCHUNK 512  // max rows per block (N <= GX*MAXCHUNK)
#define INV_TAU 2.0f
#define EPSL 1e-8f

typedef unsigned int u32;
typedef __attribute__((ext_vector_type(4))) u32 u32x4;
typedef __attribute__((ext_vector_type(8))) short s16x8;
typedef __attribute__((ext_vector_type(16))) float f32x16;

__device__ __forceinline__ u32 f2bf(float f) {
    u32 u = __builtin_bit_cast(u32, f);
    return (u + 0x7FFFu + ((u >> 16) & 1u)) >> 16;
}

// ws float layout:
// P : [2][GX][K*D]; C : [2][GX][K]; AR : [2][K*D]; lossk : [K]; scratch : [8] (probes)

__global__ __launch_bounds__(512, 4) void seg_mfma_kernel(
    const float* __restrict__ fa, const float* __restrict__ fr,
    const int* __restrict__ la, const int* __restrict__ lr,
    float* __restrict__ P, float* __restrict__ C, int N)
{
    __shared__ int lbl[MAXCHUNK];
    __shared__ int cnt[KK];

    const int tid = threadIdx.x;
    const int g = blockIdx.x, f = blockIdx.y;
    const float* __restrict__ feat = f ? fr : fa;
    const int* __restrict__ label = f ? lr : la;

    if (tid < KK) cnt[tid] = 0;

    const int chunkR = (N + GX - 1) / GX;
    const int n0 = g * chunkR;
    int rows = min(N, n0 + chunkR) - n0;
    if (rows < 0) rows = 0;

    __syncthreads();
    for (int i = tid; i < rows; i += 512) lbl[i] = label[n0 + i];
    __syncthreads();
    for (int i = tid; i < rows; i += 512) atomicAdd(&cnt[lbl[i]], 1);

    const int w = tid >> 6, lane = tid & 63;
    const int half = lane >> 5;
    const int nn = lane & 31;
    const int col0 = w * 32;

    f32x16 acc0 = {0.0f}, acc1 = {0.0f};
    const int nfull = rows / CH;

    #define LOADF(dst, t)                                                       \
    do {                                                                        \
        const float* bp_ = feat + (size_t)(n0 + (t) * CH + half * 8) * DD + col0 + nn; \
        _Pragma("unroll")                                                       \
        for (int j_ = 0; j_ < 8; ++j_) dst[j_] = bp_[j_ * DD];                  \
    } while (0)

    #define LOADL(lv, t)                                                        \
    do {                                                                        \
        const int r0_ = (t) * CH + half * 8;                                    \
        _Pragma("unroll")                                                       \
        for (int j_ = 0; j_ < 8; ++j_) lv[j_] = lbl[r0_ + j_];                  \
    } while (0)

    #define DO_CHUNK(vc, lv)                                                    \
    do {                                                                        \
        u32 a0p[4], a1p[4], bpk[4];                                             \
        _Pragma("unroll")                                                       \
        for (int p_ = 0; p_ < 4; ++p_) {                                        \
            const int j0_ = 2 * p_, j1_ = 2 * p_ + 1;                           \
            a0p[p_] = ((lv[j0_] == nn)      ? 0x3F80u : 0u) |                   \
                      ((lv[j1_] == nn)      ? 0x3F800000u : 0u);                \
            a1p[p_] = ((lv[j0_] == nn + 32) ? 0x3F80u : 0u) |                   \
                      ((lv[j1_] == nn + 32) ? 0x3F800000u : 0u);                \
            bpk[p_] = f2bf(vc[j0_]) | (f2bf(vc[j1_]) << 16);                    \
        }                                                                       \
        const s16x8 A0 = __builtin_bit_cast(s16x8, (u32x4){a0p[0], a0p[1], a0p[2], a0p[3]}); \
        const s16x8 A1 = __builtin_bit_cast(s16x8, (u32x4){a1p[0], a1p[1], a1p[2], a1p[3]}); \
        const s16x8 Bf = __builtin_bit_cast(s16x8, (u32x4){bpk[0], bpk[1], bpk[2], bpk[3]}); \
        acc0 = __builtin_amdgcn_mfma_f32_32x32x16_bf16(A0, Bf, acc0, 0, 0, 0);  \
        acc1 = __builtin_amdgcn_mfma_f32_32x32x16_bf16(A1, Bf, acc1, 0, 0, 0);  \
    } while (0)

    // depth-2 register pipeline, statically named buffers (rule #20)
    float bufA[8], bufB[8];
    int lvA[8], lvB[8];
    if (nfull > 0) LOADF(bufA, 0);
    if (nfull > 1) LOADF(bufB, 1);
    int t = 0;
    for (; t + 2 <= nfull; t += 2) {
        LOADL(lvA, t);
        DO_CHUNK(bufA, lvA);
        if (t + 2 < nfull) LOADF(bufA, t + 2);
        LOADL(lvB, t + 1);
        DO_CHUNK(bufB, lvB);
        if (t + 3 < nfull) LOADF(bufB, t + 3);
    }
    if (t < nfull) {             // odd nfull: last full chunk is in bufA
        LOADL(lvA, t);
        DO_CHUNK(bufA, lvA);
    }
    // row tail (rows % 16), clamped
    if (nfull * CH < rows) {
        const int r0 = nfull * CH + half * 8;
        float tv[8];
        int lv[8];
        #pragma unroll
        for (int j = 0; j < 8; ++j) {
            const int rr = r0 + j;
            lv[j] = (rr < rows) ? lbl[rr] : -1;
            tv[j] = feat[(size_t)(n0 + ((rr < rows) ? rr : 0)) * DD + col0 + nn];
        }
        DO_CHUNK(tv, lv);
    }
    #undef LOADF
    #undef LOADL
    #undef DO_CHUNK

    float* dstb = P + ((size_t)f * GX + g) * (KK * DD);
    #pragma unroll
    for (int rg = 0; rg < 16; ++rg) {
        const int cls = (rg & 3) + 8 * (rg >> 2) + 4 * half;
        dstb[(size_t)cls * DD + col0 + nn] = acc0[rg];
        dstb[(size_t)(cls + 32) * DD + col0 + nn] = acc1[rg];
    }
    __syncthreads();
    if (tid < KK) C[((size_t)f * GX + g) * KK + tid] = (float)cnt[tid];
}

// ---------- diagnostic probes (write only to ws scratch; output unaffected) ----------

__device__ __forceinline__ void probe_flush(float s, float* slot) {
    #pragma unroll
    for (int d = 1; d < 64; d <<= 1) s += __shfl_xor(s, d, 64);
    __shared__ float red[8];
    const int tid = threadIdx.x;
    if ((tid & 63) == 0) red[tid >> 6] = s;
    __syncthreads();
    if (tid == 0) {
        float t = 0;
        #pragma unroll
        for (int u = 0; u < 8; ++u) t += red[u];
        atomicAdd(slot, t);
    }
}

// ideal dwordx4 streaming over the SAME chunk-per-block layout
__global__ __launch_bounds__(512, 4) void probe_stream4(
    const float* __restrict__ fa, const float* __restrict__ fr,
    float* __restrict__ scratch, int N)
{
    const int tid = threadIdx.x, g = blockIdx.x, f = blockIdx.y;
    const float* feat = f ? fr : fa;
    const int chunkR = (N + GX - 1) / GX;
    const int n0 = g * chunkR;
    int rows = min(N, n0 + chunkR) - n0;
    if (rows < 0) rows = 0;
    const float4* p = (const float4*)(feat + (size_t)n0 * DD);
    const int nf4 = rows * (DD / 4);
    float s = 0.0f;
    int i = tid;
    for (; i + 512 * 7 < nf4; i += 512 * 8) {
        float4 v[8];
        #pragma unroll
        for (int u = 0; u < 8; ++u) v[u] = p[i + 512 * u];
        #pragma unroll
        for (int u = 0; u < 8; ++u) s += v[u].x + v[u].y + v[u].z + v[u].w;
    }
    for (; i < nf4; i += 512) { float4 v = p[i]; s += v.x + v.y + v.z + v.w; }
    probe_flush(s, &scratch[f]);
}

// R8's exact dword / stride-1KB pattern over the same layout (no MFMA, no labels)
__global__ __launch_bounds__(512, 4) void probe_stream1(
    const float* __restrict__ fa, const float* __restrict__ fr,
    float* __restrict__ scratch, int N)
{
    const int tid = threadIdx.x, g = blockIdx.x, f = blockIdx.y;
    const float* feat = f ? fr : fa;
    const int chunkR = (N + GX - 1) / GX;
    const int n0 = g * chunkR;
    int rows = min(N, n0 + chunkR) - n0;
    if (rows < 0) rows = 0;
    const int w = tid >> 6, lane = tid & 63;
    const int col = w * 32 + (lane & 31);
    const int half = lane >> 5;
    const int nfull = rows / CH;
    float s = 0.0f;
    for (int t = 0; t < nfull; ++t) {
        const float* bp = feat + (size_t)(n0 + t * CH + half * 8) * DD + col;
        float v[8];
        #pragma unroll
        for (int j = 0; j < 8; ++j) v[j] = bp[j * DD];
        #pragma unroll
        for (int j = 0; j < 8; ++j) s += v[j];
    }
    probe_flush(s, &scratch[2 + f]);
}

// dwordx4 streaming with grid-interleaved block->data mapping
__global__ __launch_bounds__(512, 4) void probe_ilv4(
    const float* __restrict__ fa, const float* __restrict__ fr,
    float* __restrict__ scratch, int N)
{
    const int tid = threadIdx.x, f = blockIdx.y;
    const float* feat = f ? fr : fa;
    const float4* p = (const float4*)feat;
    const size_t nf4 = (size_t)N * (DD / 4);
    const size_t stride = (size_t)GX * 512;
    size_t i = (size_t)blockIdx.x * 512 + tid;
    float s = 0.0f;
    for (; i + stride * 7 < nf4; i += stride * 8) {
        float4 v[8];
        #pragma unroll
        for (int u = 0; u < 8; ++u) v[u] = p[i + stride * u];
        #pragma unroll
        for (int u = 0; u < 8; ++u) s += v[u].x + v[u].y + v[u].z + v[u].w;
    }
    for (; i < nf4; i += stride) { float4 v = p[i]; s += v.x + v.y + v.z + v.w; }
    probe_flush(s, &scratch[4 + f]);
}

// ---------- downstream (unchanged, proven) ----------

__global__ __launch_bounds__(256) void proto_norm_kernel(
    const float* __restrict__ P, const float* __restrict__ C,
    float* __restrict__ AR, int G)
{
    const int k = blockIdx.x, f = blockIdx.y, tid = threadIdx.x;
    const float* base = P + (size_t)f * G * (KK * DD) + (size_t)k * DD + tid;

    float s = 0.0f;
    int g = 0;
    for (; g + 8 <= G; g += 8) {
        float v[8];
        #pragma unroll
        for (int u = 0; u < 8; ++u) v[u] = base[(size_t)(g + u) * (KK * DD)];
        #pragma unroll
        for (int u = 0; u < 8; ++u) s += v[u];
    }
    for (; g < G; ++g) s += base[(size_t)g * (KK * DD)];

    float c = 0.0f;
    const float* cb = C + (size_t)f * G * KK + k;
    for (int g2 = 0; g2 < G; ++g2) c += cb[(size_t)g2 * KK];

    const float m = s / c;
    float sq = m * m;
    #pragma unroll
    for (int i = 1; i < 64; i <<= 1) sq += __shfl_xor(sq, i, 64);
    __shared__ float red[4];
    const int wid = tid >> 6, lane = tid & 63;
    if (lane == 0) red[wid] = sq;
    __syncthreads();
    const float nrm = red[0] + red[1] + red[2] + red[3];
    AR[(size_t)f * KK * DD + (size_t)k * DD + tid] = m / fmaxf(sqrtf(nrm), 1e-12f);
}

__global__ __launch_bounds__(256) void loss_kernel(const float* __restrict__ AR,
                                                   float* __restrict__ lossk)
{
    const float* A = AR;
    const float* R = AR + KK * DD;
    const int k = blockIdx.x, tid = threadIdx.x;

    const float a = A[k * DD + tid];
    const float r = R[k * DD + tid];
    const float lfp = a * r * INV_TAU;
    const float fp = expf(lfp);
    float ssa = 0.0f, ssr = 0.0f;
    #pragma unroll 8
    for (int j = 0; j < KK; ++j) {
        ssa += expf(a * A[j * DD + tid] * INV_TAU);
        ssr += expf(a * R[j * DD + tid] * INV_TAU);
    }
    const float Fn = (ssa - expf(a * a * INV_TAU)) + (ssr - fp) + 2.0f * (KK - 1) * fp;
    float l = logf(Fn + EPSL) - lfp;

    #pragma unroll
    for (int i = 1; i < 64; i <<= 1) l += __shfl_xor(l, i, 64);
    __shared__ float red[4];
    const int wid = tid >> 6, lane = tid & 63;
    if (lane == 0) red[wid] = l;
    __syncthreads();
    if (tid == 0) lossk[k] = (red[0] + red[1] + red[2] + red[3]) * (1.0f / DD);
}

__global__ void final_kernel(const float* __restrict__ lossk, float* __restrict__ out)
{
    float v = lossk[threadIdx.x];
    #pragma unroll
    for (int i = 1; i < 64; i <<= 1) v += __shfl_xor(v, i, 64);
    if (threadIdx.x == 0) out[0] = v;
}

extern "C" void kernel_launch(void* const* d_in, const int* in_sizes, int n_in,
                              void* d_out, int out_size, void* d_ws, size_t ws_size,
                              hipStream_t stream)
{
    const float* fa = (const float*)d_in[0];
    const float* fr = (const float*)d_in[1];
    const int* la = (const int*)d_in[2];
    const int* lr = (const int*)d_in[3];
    float* ws = (float*)d_ws;
    float* out = (float*)d_out;
    const int N = in_sizes[2];

    float* P = ws;                                  // [2][GX][K*D]
    float* C = P + 2L * GX * KK * DD;               // [2][GX][K]
    float* AR = C + 2L * GX * KK;                   // [2][K*D]
    float* lossk = AR + 2L * KK * DD;               // [K]
    float* scratch = lossk + KK;                    // [8] probe slots

    hipMemsetAsync(scratch, 0, 8 * sizeof(float), stream);

    seg_mfma_kernel<<<dim3(GX, 2), 512, 0, stream>>>(fa, fr, la, lr, P, C, N);
    proto_norm_kernel<<<dim3(KK, 2), 256, 0, stream>>>(P, C, AR, GX);
    loss_kernel<<<KK, 256, 0, stream>>>(AR, lossk);
    final_kernel<<<1, 64, 0, stream>>>(lossk, out);

    // diagnostic probes (after output is produced; write only to scratch)
    probe_stream4<<<dim3(GX, 2), 512, 0, stream>>>(fa, fr, scratch, N);
    probe_stream1<<<dim3(GX, 2), 512, 0, stream>>>(fa, fr, scratch, N);
    probe_ilv4<<<dim3(GX, 2), 512, 0, stream>>>(fa, fr, scratch, N);
}